// Round 1
// baseline (390.126 us; speedup 1.0000x reference)
//
#include <hip/hip_runtime.h>

#define L 4096
#define CCH 256
#define NB 4

// ---------------------------------------------------------------------------
// Dual conv1x1 GEMM: y1[b,o,l] = b1[o] + sum_c w1[o,c] x[b,c,l]; same for y2.
// Tile 64(o) x 64(l), BK=16, 256 threads, 4x4 per thread.
// ---------------------------------------------------------------------------
__global__ __launch_bounds__(256) void dual_gemm_k(
    const float* __restrict__ x,
    const float* __restrict__ w1, const float* __restrict__ b1,
    const float* __restrict__ w2, const float* __restrict__ b2,
    float* __restrict__ y1, float* __restrict__ y2)
{
    __shared__ float sW1[16][64];
    __shared__ float sW2[16][64];
    __shared__ float sX [16][64];

    const int tid = threadIdx.x;
    const int l0 = blockIdx.x * 64;
    const int o0 = blockIdx.y * 64;
    const int b  = blockIdx.z;
    const int tx = tid & 15, ty = tid >> 4;

    const float* xb = x + (size_t)b * CCH * L;

    float acc1[4][4] = {}; float acc2[4][4] = {};

    const int wo = tid >> 2, wk = (tid & 3) * 4;   // W tile load map
    const int xk = tid >> 4, xl = (tid & 15) * 4;  // X tile load map

    for (int k0 = 0; k0 < CCH; k0 += 16) {
        float4 wv1 = *(const float4*)&w1[(size_t)(o0 + wo) * CCH + k0 + wk];
        float4 wv2 = *(const float4*)&w2[(size_t)(o0 + wo) * CCH + k0 + wk];
        float4 xv  = *(const float4*)&xb[(size_t)(k0 + xk) * L + l0 + xl];
        sW1[wk+0][wo] = wv1.x; sW1[wk+1][wo] = wv1.y; sW1[wk+2][wo] = wv1.z; sW1[wk+3][wo] = wv1.w;
        sW2[wk+0][wo] = wv2.x; sW2[wk+1][wo] = wv2.y; sW2[wk+2][wo] = wv2.z; sW2[wk+3][wo] = wv2.w;
        *(float4*)&sX[xk][xl] = xv;
        __syncthreads();
        #pragma unroll
        for (int k = 0; k < 16; ++k) {
            float4 a1 = *(const float4*)&sW1[k][ty * 4];
            float4 a2 = *(const float4*)&sW2[k][ty * 4];
            float4 bx = *(const float4*)&sX [k][tx * 4];
            float a1v[4] = {a1.x, a1.y, a1.z, a1.w};
            float a2v[4] = {a2.x, a2.y, a2.z, a2.w};
            float bv [4] = {bx.x, bx.y, bx.z, bx.w};
            #pragma unroll
            for (int i = 0; i < 4; ++i)
                #pragma unroll
                for (int j = 0; j < 4; ++j) {
                    acc1[i][j] = fmaf(a1v[i], bv[j], acc1[i][j]);
                    acc2[i][j] = fmaf(a2v[i], bv[j], acc2[i][j]);
                }
        }
        __syncthreads();
    }

    #pragma unroll
    for (int i = 0; i < 4; ++i) {
        int o = o0 + ty * 4 + i;
        float bb1 = b1[o], bb2 = b2[o];
        float4 r1 = make_float4(acc1[i][0] + bb1, acc1[i][1] + bb1, acc1[i][2] + bb1, acc1[i][3] + bb1);
        float4 r2 = make_float4(acc2[i][0] + bb2, acc2[i][1] + bb2, acc2[i][2] + bb2, acc2[i][3] + bb2);
        size_t off = ((size_t)b * CCH + o) * L + l0 + tx * 4;
        *(float4*)&y1[off] = r1;
        *(float4*)&y2[off] = r2;
    }
}

// ---------------------------------------------------------------------------
// Single conv1x1 GEMM (final layer)
// ---------------------------------------------------------------------------
__global__ __launch_bounds__(256) void single_gemm_k(
    const float* __restrict__ x,
    const float* __restrict__ w, const float* __restrict__ bb,
    float* __restrict__ y)
{
    __shared__ float sW[16][64];
    __shared__ float sX[16][64];

    const int tid = threadIdx.x;
    const int l0 = blockIdx.x * 64;
    const int o0 = blockIdx.y * 64;
    const int b  = blockIdx.z;
    const int tx = tid & 15, ty = tid >> 4;

    const float* xb = x + (size_t)b * CCH * L;
    float acc[4][4] = {};

    const int wo = tid >> 2, wk = (tid & 3) * 4;
    const int xk = tid >> 4, xl = (tid & 15) * 4;

    for (int k0 = 0; k0 < CCH; k0 += 16) {
        float4 wv = *(const float4*)&w[(size_t)(o0 + wo) * CCH + k0 + wk];
        float4 xv = *(const float4*)&xb[(size_t)(k0 + xk) * L + l0 + xl];
        sW[wk+0][wo] = wv.x; sW[wk+1][wo] = wv.y; sW[wk+2][wo] = wv.z; sW[wk+3][wo] = wv.w;
        *(float4*)&sX[xk][xl] = xv;
        __syncthreads();
        #pragma unroll
        for (int k = 0; k < 16; ++k) {
            float4 a = *(const float4*)&sW[k][ty * 4];
            float4 bx = *(const float4*)&sX[k][tx * 4];
            float av[4] = {a.x, a.y, a.z, a.w};
            float bv[4] = {bx.x, bx.y, bx.z, bx.w};
            #pragma unroll
            for (int i = 0; i < 4; ++i)
                #pragma unroll
                for (int j = 0; j < 4; ++j)
                    acc[i][j] = fmaf(av[i], bv[j], acc[i][j]);
        }
        __syncthreads();
    }

    #pragma unroll
    for (int i = 0; i < 4; ++i) {
        int o = o0 + ty * 4 + i;
        float b0 = bb[o];
        float4 r = make_float4(acc[i][0] + b0, acc[i][1] + b0, acc[i][2] + b0, acc[i][3] + b0);
        *(float4*)&y[((size_t)b * CCH + o) * L + l0 + tx * 4] = r;
    }
}

// ---------------------------------------------------------------------------
// BatchNorm stats: per channel c over (B, L): scale = g*rstd, shift = be - mu*g*rstd
// ---------------------------------------------------------------------------
__global__ __launch_bounds__(256) void bn_stats_k(
    const float* __restrict__ y, const float* __restrict__ gamma,
    const float* __restrict__ beta,
    float* __restrict__ scale, float* __restrict__ shift)
{
    const int c = blockIdx.x, tid = threadIdx.x;
    float s = 0.f, s2 = 0.f;
    for (int b = 0; b < NB; ++b) {
        const float4* p = (const float4*)(y + ((size_t)b * CCH + c) * L);
        #pragma unroll
        for (int r = 0; r < 4; ++r) {
            float4 v = p[r * 256 + tid];
            s  += v.x + v.y + v.z + v.w;
            s2 += v.x * v.x + v.y * v.y + v.z * v.z + v.w * v.w;
        }
    }
    #pragma unroll
    for (int off = 32; off > 0; off >>= 1) {
        s  += __shfl_down(s, off);
        s2 += __shfl_down(s2, off);
    }
    __shared__ float red[2][4];
    if ((tid & 63) == 0) { red[0][tid >> 6] = s; red[1][tid >> 6] = s2; }
    __syncthreads();
    if (tid == 0) {
        float S  = red[0][0] + red[0][1] + red[0][2] + red[0][3];
        float S2 = red[1][0] + red[1][1] + red[1][2] + red[1][3];
        const float invN = 1.f / (NB * (float)L);
        float mean = S * invN;
        float var  = S2 * invN - mean * mean;
        float rstd = rsqrtf(var + 1e-5f);
        float g = gamma[c];
        scale[c] = g * rstd;
        shift[c] = beta[c] - mean * g * rstd;
    }
}

// ---------------------------------------------------------------------------
// Attention: one block per (b,c). Stages BN+ReLU'd key/query images + x image
// in LDS; for each of the 4096 consecutive-9 windows of the flattened [9,L]
// unfold, softmax(k*qc + kc*q) * x scattered by (flat index mod L).
// Writes pre in-place over y2's slice.
// ---------------------------------------------------------------------------
__global__ __launch_bounds__(256) void attention_k(
    const float* __restrict__ x,
    const float* __restrict__ y1,
    const float* y2,
    const float* __restrict__ s1sc, const float* __restrict__ s1sh,
    const float* __restrict__ s2sc, const float* __restrict__ s2sh,
    float* pre)
{
    __shared__ float sK[L];
    __shared__ float sQ[L];
    __shared__ float sXv[L];
    __shared__ float sOut[L];

    const int bc = blockIdx.x;
    const int tid = threadIdx.x;
    const int ch = bc & 255;
    const size_t off = (size_t)bc * L;

    const float sc1 = s1sc[ch], sh1 = s1sh[ch];
    const float sc2 = s2sc[ch], sh2 = s2sh[ch];

    const float4* k4 = (const float4*)(y1 + off);
    const float4* q4 = (const float4*)(y2 + off);
    const float4* x4 = (const float4*)(x + off);

    #pragma unroll
    for (int r = 0; r < 4; ++r) {
        int i = r * 256 + tid;
        float4 a = k4[i];
        a.x = fmaxf(fmaf(a.x, sc1, sh1), 0.f);
        a.y = fmaxf(fmaf(a.y, sc1, sh1), 0.f);
        a.z = fmaxf(fmaf(a.z, sc1, sh1), 0.f);
        a.w = fmaxf(fmaf(a.w, sc1, sh1), 0.f);
        ((float4*)sK)[i] = a;
        float4 q = q4[i];
        q.x = fmaxf(fmaf(q.x, sc2, sh2), 0.f);
        q.y = fmaxf(fmaf(q.y, sc2, sh2), 0.f);
        q.z = fmaxf(fmaf(q.z, sc2, sh2), 0.f);
        q.w = fmaxf(fmaf(q.w, sc2, sh2), 0.f);
        ((float4*)sQ)[i] = q;
        ((float4*)sXv)[i] = x4[i];
        ((float4*)sOut)[i] = make_float4(0.f, 0.f, 0.f, 0.f);
    }
    __syncthreads();

    for (int lp = tid; lp < L; lp += 256) {
        const int base = 9 * lp;
        float kv[9], qv[9], xv[9];
        #pragma unroll
        for (int j = 0; j < 9; ++j) {
            int f = base + j;
            int t = f >> 12;          // which of the 9 unfold taps
            int l = f & 4095;         // spatial position
            int di = (t * 86) >> 8;   // t/3 for t in [0,9)
            int dj = t - di * 3;
            int ii = (l >> 6) + di - 1;
            int jj = (l & 63) + dj - 1;
            bool ok = ((unsigned)ii < 64u) && ((unsigned)jj < 64u);
            int src = ((ii << 6) + jj) & 4095;
            float kj = sK[src], qj = sQ[src], xj = sXv[src];
            kv[j] = ok ? kj : 0.f;
            qv[j] = ok ? qj : 0.f;
            xv[j] = ok ? xj : 0.f;
        }
        const float kc = kv[4], qc = qv[4];
        float lg[9], m = -1e30f;
        #pragma unroll
        for (int j = 0; j < 9; ++j) {
            lg[j] = kv[j] * qc + kc * qv[j];
            m = fmaxf(m, lg[j]);
        }
        float e[9], s = 0.f;
        #pragma unroll
        for (int j = 0; j < 9; ++j) {
            e[j] = __expf(lg[j] - m);
            s += e[j];
        }
        float inv = __builtin_amdgcn_rcpf(s);
        #pragma unroll
        for (int j = 0; j < 9; ++j) {
            atomicAdd(&sOut[(base + j) & 4095], e[j] * inv * xv[j]);
        }
    }
    __syncthreads();

    #pragma unroll
    for (int r = 0; r < 4; ++r) {
        int i = r * 256 + tid;
        ((float4*)(pre + off))[i] = ((const float4*)sOut)[i];
    }
}

// ---------------------------------------------------------------------------
// Final BN apply + ReLU
// ---------------------------------------------------------------------------
__global__ __launch_bounds__(256) void bn_apply_k(
    const float* __restrict__ yf,
    const float* __restrict__ scale, const float* __restrict__ shift,
    float* __restrict__ out)
{
    int i = blockIdx.x * 256 + threadIdx.x;     // float4 index
    int o = (i >> 10) & 255;                    // channel
    float sc = scale[o], sh = shift[o];
    float4 v = ((const float4*)yf)[i];
    v.x = fmaxf(fmaf(v.x, sc, sh), 0.f);
    v.y = fmaxf(fmaf(v.y, sc, sh), 0.f);
    v.z = fmaxf(fmaf(v.z, sc, sh), 0.f);
    v.w = fmaxf(fmaf(v.w, sc, sh), 0.f);
    ((float4*)out)[i] = v;
}

// ---------------------------------------------------------------------------
extern "C" void kernel_launch(void* const* d_in, const int* in_sizes, int n_in,
                              void* d_out, int out_size, void* d_ws, size_t ws_size,
                              hipStream_t stream) {
    const float* x   = (const float*)d_in[0];
    const float* w1  = (const float*)d_in[1];
    const float* b1  = (const float*)d_in[2];
    const float* g1  = (const float*)d_in[3];
    const float* be1 = (const float*)d_in[4];
    const float* w2  = (const float*)d_in[5];
    const float* b2  = (const float*)d_in[6];
    const float* g2  = (const float*)d_in[7];
    const float* be2 = (const float*)d_in[8];
    const float* wf  = (const float*)d_in[9];
    const float* bf  = (const float*)d_in[10];
    const float* gf  = (const float*)d_in[11];
    const float* bef = (const float*)d_in[12];
    float* out = (float*)d_out;

    float* ws = (float*)d_ws;
    const size_t NEL = (size_t)NB * CCH * L;   // 4194304
    float* y1 = ws;                 // raw conv1 out; later reused for yf
    float* y2 = ws + NEL;           // raw conv2 out; later reused for pre
    float* st = ws + 2 * NEL;       // stats: 6 x 256
    float* s1sc = st,        *s1sh = st + 256;
    float* s2sc = st + 512,  *s2sh = st + 768;
    float* sfsc = st + 1024, *sfsh = st + 1280;

    dim3 gg(64, 4, 4);
    dual_gemm_k<<<gg, 256, 0, stream>>>(x, w1, b1, w2, b2, y1, y2);
    bn_stats_k<<<256, 256, 0, stream>>>(y1, g1, be1, s1sc, s1sh);
    bn_stats_k<<<256, 256, 0, stream>>>(y2, g2, be2, s2sc, s2sh);
    attention_k<<<NB * CCH, 256, 0, stream>>>(x, y1, y2, s1sc, s1sh, s2sc, s2sh, /*pre=*/y2);
    single_gemm_k<<<gg, 256, 0, stream>>>(/*pre=*/y2, wf, bf, /*yf=*/y1);
    bn_stats_k<<<256, 256, 0, stream>>>(y1, gf, bef, sfsc, sfsh);
    bn_apply_k<<<4096, 256, 0, stream>>>(y1, sfsc, sfsh, out);
}